// Round 12
// baseline (274.297 us; speedup 1.0000x reference)
//
#include <hip/hip_runtime.h>
#include <hip/hip_bf16.h>
#include <stdint.h>

#define B_    8
#define S_    4096
#define D_    1536
#define ORG_  4
#define OUT_  2048

typedef __bf16 bf16;
typedef __attribute__((ext_vector_type(8)))  bf16  bf16x8;
typedef __attribute__((ext_vector_type(4)))  float f32x4n;   // native vec for nt builtins
typedef __attribute__((ext_vector_type(16))) float f32x16;

#define BK64 64
#define NKT  (D_ / BK64)   // 24 K-tiles

#define XBLKS 2048                       // blocks doing the x-stream part
#define WTBLK (ORG_ * (OUT_/32) * (D_/32))  // 12288 blocks doing w-transpose

// ---- merged convert: x f32->bf16 stream  +  w f32 [O][D][OUT] -> bf16 [O][OUT][D]
// x and w are read-once -> nontemporal loads (keep xb/wt resident for GEMM).
__global__ void k_cvt_all(const float* __restrict__ x, bf16* __restrict__ xb,
                          const float* __restrict__ w, bf16* __restrict__ wt) {
  __shared__ float tile[32][33];
  const int bx = blockIdx.x;
  const int tid = threadIdx.x;

  if (bx < XBLKS) {
    // -------- x part: 8 elems/thread/iter, grid-stride --------
    const long n8 = (long)B_ * S_ * D_ / 8;   // 6,291,456
    long i = (long)bx * blockDim.x + tid;
    const long stride = (long)XBLKS * blockDim.x;
    for (; i < n8; i += stride) {
      const f32x4n* p = (const f32x4n*)(x + i * 8);
      f32x4n a = __builtin_nontemporal_load(p);
      f32x4n b = __builtin_nontemporal_load(p + 1);
      bf16x8 v;
      v[0] = (bf16)a[0]; v[1] = (bf16)a[1]; v[2] = (bf16)a[2]; v[3] = (bf16)a[3];
      v[4] = (bf16)b[0]; v[5] = (bf16)b[1]; v[6] = (bf16)b[2]; v[7] = (bf16)b[3];
      *(bf16x8*)(xb + i * 8) = v;
    }
  } else {
    // -------- w part: 32x32 tile transpose --------
    const int q   = bx - XBLKS;
    const int org = q / ((OUT_/32) * (D_/32));
    const int rem = q % ((OUT_/32) * (D_/32));
    const int d0  = (rem / (OUT_/32)) * 32;
    const int n0  = (rem % (OUT_/32)) * 32;
    const int tx = tid & 31, ty = tid >> 5;   // 32 x 8
    const float* wsrc = w + (size_t)org * D_ * OUT_;
    bf16* wdst = wt + (size_t)org * OUT_ * D_;
#pragma unroll
    for (int j = 0; j < 32; j += 8)
      tile[ty + j][tx] = __builtin_nontemporal_load(
          wsrc + (size_t)(d0 + ty + j) * OUT_ + (n0 + tx));
    __syncthreads();
#pragma unroll
    for (int j = 0; j < 32; j += 8)
      wdst[(size_t)(n0 + ty + j) * D_ + (d0 + tx)] = (bf16)tile[tx][ty + j];
  }
}

// ----- 256x256 8-phase bf16 MFMA GEMM, 32x32x16, ONE barrier per phase ------
// A = xb[batch] : [S][D] row-major;  B = wt[org] : [OUT][D] row-major (B^T)
// C[m][n] = sum_k A[m][k]*B[n][k]  + bias[n]
// Schedule = round-8 verified best (one barrier/phase, vmcnt(4) checkpoints,
// plain epilogue stores). cvt keeps nt loads (round-11 isolated win).
__global__ __launch_bounds__(512, 2)
void k_gemm256(const bf16* __restrict__ xb, const bf16* __restrict__ wt,
               const int* __restrict__ oidx, const float* __restrict__ bias,
               float* __restrict__ out) {
  __shared__ __align__(16) char smem[131072];   // A: 2x32KB, B: 2x32KB
  char* const ldsA = smem;
  char* const ldsB = smem + 65536;

  const int batch = blockIdx.y;
  const int bx = blockIdx.x;
  // T1: XCD-aware swizzle (128 tiles, 8 XCDs). XCD = bx&7 owns one tn column.
  const int swz = (bx & 7) * 16 + (bx >> 3);
  const int tn = swz >> 4, tm = swz & 15;
  const int m0 = tm * 256, n0 = tn * 256;
  const int org = oidx[batch];

  const bf16* Ag = xb + (size_t)batch * S_ * D_ + (size_t)m0 * D_;
  const bf16* Bg = wt + (size_t)org * OUT_ * D_ + (size_t)n0 * D_;

  const int tid  = threadIdx.x;
  const int lane = tid & 63, wv = tid >> 6;
  const int wr = wv >> 2, wc = wv & 3;        // 2x4 wave grid, per-wave 128x64 out
  const int l31 = lane & 31, hi = lane >> 5;

  // Read-side swizzle key(r) = (r&7)^((r>>3)&3) (verified conflict-free r5).
  const int xorv = ((lane & 7) ^ ((lane >> 3) & 3)) << 4;
  const int off[4] = { (0  + hi * 16) ^ xorv, (32 + hi * 16) ^ xorv,
                       (64 + hi * 16) ^ xorv, (96 + hi * 16) ^ xorv };
  const int arow = (wr * 128 + l31) * 128;    // + mt*4096
  const int brow = (wc * 64  + l31) * 128;    // + nt*4096

  // Stage-side: linear LDS dest + inverse-swizzled per-lane GLOBAL source.
  const int srow = tid >> 3;
  const int scol = (((tid & 7) ^ ((tid >> 3) & 7) ^ ((tid >> 6) & 3))) << 3;
  const int soff = wv * 1024;

#define LDA(v, mt, ks) (*(const bf16x8*)(ldsA + (v)*32768 + arow + (mt)*4096 + off[ks]))
#define LDB(v, nt, ks) (*(const bf16x8*)(ldsB + (v)*32768 + brow + (nt)*4096 + off[ks]))

#define STAGE_HALF(gptr, ldsbase, h, kb) do {                                            \
    __builtin_amdgcn_global_load_lds(                                                    \
      (__attribute__((address_space(1))) void*)((gptr) + (size_t)((h)*128 + srow) * D_ + (kb) + scol), \
      (__attribute__((address_space(3))) void*)((ldsbase) + (h)*16384 + soff), 16, 0, 0);\
    __builtin_amdgcn_global_load_lds(                                                    \
      (__attribute__((address_space(1))) void*)((gptr) + (size_t)((h)*128 + 64 + srow) * D_ + (kb) + scol), \
      (__attribute__((address_space(3))) void*)((ldsbase) + (h)*16384 + 8192 + soff), 16, 0, 0); \
  } while (0)

#define SBAR()  __builtin_amdgcn_s_barrier()
#define LGK0()  asm volatile("s_waitcnt lgkmcnt(0)" ::: "memory")
#define VMC4()  asm volatile("s_waitcnt vmcnt(4)" ::: "memory")
#define VMC0()  asm volatile("s_waitcnt vmcnt(0)" ::: "memory")
#define PRIO(p) __builtin_amdgcn_s_setprio(p)

  bf16x8 a[2][4], b0[4], b1[4];
  f32x16 acc[4][2];
#pragma unroll
  for (int mt = 0; mt < 4; ++mt)
#pragma unroll
    for (int nt = 0; nt < 2; ++nt)
#pragma unroll
      for (int rr = 0; rr < 16; ++rr) acc[mt][nt][rr] = 0.f;

#define READ_A2(v, mbase) do { _Pragma("unroll") for (int mm = 0; mm < 2; ++mm) \
    _Pragma("unroll") for (int ks = 0; ks < 4; ++ks) \
      a[mm][ks] = LDA(v, (mbase) + mm, ks); } while (0)
#define READ_B4(v, nt, bb) do { _Pragma("unroll") for (int ks = 0; ks < 4; ++ks) \
      bb[ks] = LDB(v, nt, ks); } while (0)
#define MFMA_O(mbase, nt, bb) do { \
    _Pragma("unroll") for (int mm = 0; mm < 2; ++mm) \
    _Pragma("unroll") for (int ks = 0; ks < 4; ++ks) \
      acc[(mbase)+mm][nt] = __builtin_amdgcn_mfma_f32_32x32x16_bf16( \
          a[mm][ks], bb[ks], acc[(mbase)+mm][nt], 0, 0, 0); } while (0)

  // ---- prologue: tile0 B+A, tile1 B (6 halves = 12 loads); newest 2 halves
  // (tile1 B) may stay outstanding at the barrier.
  STAGE_HALF(Bg, ldsB, 0, 0);
  STAGE_HALF(Bg, ldsB, 1, 0);
  STAGE_HALF(Ag, ldsA, 0, 0);
  STAGE_HALF(Ag, ldsA, 1, 0);
  STAGE_HALF(Bg, ldsB + 32768, 0, BK64);
  STAGE_HALF(Bg, ldsB + 32768, 1, BK64);
  VMC4();
  SBAR();

  for (int i = 0; i < NKT / 2; ++i) {
    const int k1 = (2 * i + 1) * BK64;
    int t2 = 2 * i + 2; if (t2 > NKT - 1) t2 = NKT - 1;   // clamp, never skip:
    int t3 = 2 * i + 3; if (t3 > NKT - 1) t3 = NKT - 1;   // keeps vmcnt math exact
    const int k2 = t2 * BK64, k3 = t3 * BK64;

    // P1: tile 2i, quad(mt0-1 x nt0); stage A-half0(2i+1) -> buf1
    READ_A2(0, 0); READ_B4(0, 0, b0);
    STAGE_HALF(Ag, ldsA + 32768, 0, k1);
    PRIO(1); MFMA_O(0, 0, b0); PRIO(0);
    LGK0(); SBAR();
    // P2: quad(mt0-1 x nt1); stage A-half1(2i+1) -> buf1
    READ_B4(0, 1, b1);
    STAGE_HALF(Ag, ldsA + 32768, 1, k1);
    PRIO(1); MFMA_O(0, 1, b1); PRIO(0);
    LGK0(); SBAR();
    // P3: quad(mt2-3 x nt0); stage B-half0(2i+2) -> buf0
    READ_A2(0, 2);
    STAGE_HALF(Bg, ldsB, 0, k2);
    PRIO(1); MFMA_O(2, 0, b0); PRIO(0);
    LGK0(); SBAR();
    // P4: quad(mt2-3 x nt1); stage B-half1(2i+2); checkpoint vmcnt(4)
    STAGE_HALF(Bg, ldsB, 1, k2);
    PRIO(1); MFMA_O(2, 1, b1); PRIO(0);
    VMC4();
    SBAR();
    // P5: tile 2i+1, quad(mt0-1 x nt0); stage A-half0(2i+2) -> buf0
    READ_A2(1, 0); READ_B4(1, 0, b0);
    STAGE_HALF(Ag, ldsA, 0, k2);
    PRIO(1); MFMA_O(0, 0, b0); PRIO(0);
    LGK0(); SBAR();
    // P6: quad(mt0-1 x nt1); stage A-half1(2i+2) -> buf0
    READ_B4(1, 1, b1);
    STAGE_HALF(Ag, ldsA, 1, k2);
    PRIO(1); MFMA_O(0, 1, b1); PRIO(0);
    LGK0(); SBAR();
    // P7: quad(mt2-3 x nt0); stage B-half0(2i+3) -> buf1
    READ_A2(1, 2);
    STAGE_HALF(Bg, ldsB + 32768, 0, k3);
    PRIO(1); MFMA_O(2, 0, b0); PRIO(0);
    LGK0(); SBAR();
    // P8: quad(mt2-3 x nt1); stage B-half1(2i+3); checkpoint vmcnt(4)
    STAGE_HALF(Bg, ldsB + 32768, 1, k3);
    PRIO(1); MFMA_O(2, 1, b1); PRIO(0);
    VMC4();
    SBAR();
  }

  VMC0();  // drain trailing (clamped) stages before stores

  // epilogue: 32x32 C/D layout col = lane&31, row = (reg&3)+8*(reg>>2)+4*(lane>>5)
  // Plain stores (round-8 verified; nt stores slowed the profiled GEMM r11).
  float* Og = out + (size_t)batch * S_ * OUT_ + (size_t)m0 * OUT_ + n0;
  const float* bbase = bias + (size_t)org * OUT_ + n0;
#pragma unroll
  for (int nt = 0; nt < 2; ++nt) {
    const int col = wc * 64 + nt * 32 + l31;
    const float bv = bbase[col];
#pragma unroll
    for (int mt = 0; mt < 4; ++mt) {
#pragma unroll
      for (int rr = 0; rr < 16; ++rr) {
        const int row = wr * 128 + mt * 32 + 4 * hi + (rr & 3) + 8 * (rr >> 2);
        Og[(size_t)row * OUT_ + col] = acc[mt][nt][rr] + bv;
      }
    }
  }
#undef LDA
#undef LDB
#undef STAGE_HALF
#undef SBAR
#undef LGK0
#undef VMC4
#undef VMC0
#undef PRIO
#undef READ_A2
#undef READ_B4
#undef MFMA_O
}

// ---------------- fallback: naive fp32 (only if ws too small) ---------------
__global__ void k_gemm_fallback(const float* __restrict__ x, const int* __restrict__ oidx,
                                const float* __restrict__ w, const float* __restrict__ bias,
                                float* __restrict__ out) {
  const int b = blockIdx.z;
  const int org = oidx[b];
  const int n = blockIdx.x * 64 + threadIdx.x;
  const int m = blockIdx.y * 4 + threadIdx.y;
  const float* xr = x + ((size_t)b * S_ + m) * D_;
  const float* wp = w + (size_t)org * D_ * OUT_ + n;
  float acc = 0.f;
  for (int k = 0; k < D_; ++k) acc += xr[k] * wp[(size_t)k * OUT_];
  out[((size_t)b * S_ + m) * OUT_ + n] = acc + bias[(size_t)org * OUT_ + n];
}

extern "C" void kernel_launch(void* const* d_in, const int* in_sizes, int n_in,
                              void* d_out, int out_size, void* d_ws, size_t ws_size,
                              hipStream_t stream) {
  const float* x    = (const float*)d_in[0];
  const int*   oidx = (const int*)d_in[1];
  const float* w    = (const float*)d_in[2];
  const float* bias = (const float*)d_in[3];
  float* out = (float*)d_out;

  const size_t xb_elems = (size_t)B_ * S_ * D_;      // 50,331,648
  const size_t wt_elems = (size_t)ORG_ * OUT_ * D_;  // 12,582,912
  const size_t need = (xb_elems + wt_elems) * sizeof(bf16);  // ~126 MB

  if (ws_size < need) {
    dim3 g(OUT_ / 64, S_ / 4, B_);
    k_gemm_fallback<<<g, dim3(64, 4), 0, stream>>>(x, oidx, w, bias, out);
    return;
  }

  bf16* xb = (bf16*)d_ws;
  bf16* wt = xb + xb_elems;

  k_cvt_all<<<XBLKS + WTBLK, 256, 0, stream>>>(x, xb, w, wt);
  dim3 gg(128, B_);
  k_gemm256<<<gg, 512, 0, stream>>>(xb, wt, oidx, bias, out);
}

// Round 13
// 272.281 us; speedup vs baseline: 1.0074x; 1.0074x over previous
//
#include <hip/hip_runtime.h>
#include <hip/hip_bf16.h>
#include <stdint.h>

#define B_    8
#define S_    4096
#define D_    1536
#define ORG_  4
#define OUT_  2048

typedef __bf16 bf16;
typedef __attribute__((ext_vector_type(8)))  bf16  bf16x8;
typedef __attribute__((ext_vector_type(4)))  float f32x4n;   // native vec for nt builtins
typedef __attribute__((ext_vector_type(16))) float f32x16;

#define BK64 64
#define NKT  (D_ / BK64)   // 24 K-tiles

#define XBLKS 2048                       // blocks doing the x-stream part
#define WTBLK (ORG_ * (OUT_/32) * (D_/32))  // 12288 blocks doing w-transpose

// ---- merged convert: x f32->bf16 stream  +  w f32 [O][D][OUT] -> bf16 [O][OUT][D]
// x and w are read-once -> nontemporal loads (keep xb/wt resident for GEMM).
__global__ void k_cvt_all(const float* __restrict__ x, bf16* __restrict__ xb,
                          const float* __restrict__ w, bf16* __restrict__ wt) {
  __shared__ float tile[32][33];
  const int bx = blockIdx.x;
  const int tid = threadIdx.x;

  if (bx < XBLKS) {
    // -------- x part: 8 elems/thread/iter, grid-stride --------
    const long n8 = (long)B_ * S_ * D_ / 8;   // 6,291,456
    long i = (long)bx * blockDim.x + tid;
    const long stride = (long)XBLKS * blockDim.x;
    for (; i < n8; i += stride) {
      const f32x4n* p = (const f32x4n*)(x + i * 8);
      f32x4n a = __builtin_nontemporal_load(p);
      f32x4n b = __builtin_nontemporal_load(p + 1);
      bf16x8 v;
      v[0] = (bf16)a[0]; v[1] = (bf16)a[1]; v[2] = (bf16)a[2]; v[3] = (bf16)a[3];
      v[4] = (bf16)b[0]; v[5] = (bf16)b[1]; v[6] = (bf16)b[2]; v[7] = (bf16)b[3];
      *(bf16x8*)(xb + i * 8) = v;
    }
  } else {
    // -------- w part: 32x32 tile transpose --------
    const int q   = bx - XBLKS;
    const int org = q / ((OUT_/32) * (D_/32));
    const int rem = q % ((OUT_/32) * (D_/32));
    const int d0  = (rem / (OUT_/32)) * 32;
    const int n0  = (rem % (OUT_/32)) * 32;
    const int tx = tid & 31, ty = tid >> 5;   // 32 x 8
    const float* wsrc = w + (size_t)org * D_ * OUT_;
    bf16* wdst = wt + (size_t)org * OUT_ * D_;
#pragma unroll
    for (int j = 0; j < 32; j += 8)
      tile[ty + j][tx] = __builtin_nontemporal_load(
          wsrc + (size_t)(d0 + ty + j) * OUT_ + (n0 + tx));
    __syncthreads();
#pragma unroll
    for (int j = 0; j < 32; j += 8)
      wdst[(size_t)(n0 + ty + j) * D_ + (d0 + tx)] = (bf16)tile[tx][ty + j];
  }
}

// ----- 256x256 8-phase bf16 MFMA GEMM, 32x32x16, ONE barrier per phase ------
// A = xb[batch] : [S][D] row-major;  B = wt[org] : [OUT][D] row-major (B^T)
// C[m][n] = sum_k A[m][k]*B[n][k]  + bias[n]
// Round-8 verified schedule. NEW r13: (1) MFMA_O interleaves ks-outer/mm-inner
// (same accumulation order per acc -> bit-identical; breaks dependent chains);
// (2) last iteration peeled: main loop never clamps, the 12 dead re-stages are
// gone, and the epilogue needs no vmcnt drain.
__global__ __launch_bounds__(512, 2)
void k_gemm256(const bf16* __restrict__ xb, const bf16* __restrict__ wt,
               const int* __restrict__ oidx, const float* __restrict__ bias,
               float* __restrict__ out) {
  __shared__ __align__(16) char smem[131072];   // A: 2x32KB, B: 2x32KB
  char* const ldsA = smem;
  char* const ldsB = smem + 65536;

  const int batch = blockIdx.y;
  const int bx = blockIdx.x;
  // T1: XCD-aware swizzle (128 tiles, 8 XCDs). XCD = bx&7 owns one tn column.
  const int swz = (bx & 7) * 16 + (bx >> 3);
  const int tn = swz >> 4, tm = swz & 15;
  const int m0 = tm * 256, n0 = tn * 256;
  const int org = oidx[batch];

  const bf16* Ag = xb + (size_t)batch * S_ * D_ + (size_t)m0 * D_;
  const bf16* Bg = wt + (size_t)org * OUT_ * D_ + (size_t)n0 * D_;

  const int tid  = threadIdx.x;
  const int lane = tid & 63, wv = tid >> 6;
  const int wr = wv >> 2, wc = wv & 3;        // 2x4 wave grid, per-wave 128x64 out
  const int l31 = lane & 31, hi = lane >> 5;

  // Read-side swizzle key(r) = (r&7)^((r>>3)&3) (verified conflict-free r5).
  const int xorv = ((lane & 7) ^ ((lane >> 3) & 3)) << 4;
  const int off[4] = { (0  + hi * 16) ^ xorv, (32 + hi * 16) ^ xorv,
                       (64 + hi * 16) ^ xorv, (96 + hi * 16) ^ xorv };
  const int arow = (wr * 128 + l31) * 128;    // + mt*4096
  const int brow = (wc * 64  + l31) * 128;    // + nt*4096

  // Stage-side: linear LDS dest + inverse-swizzled per-lane GLOBAL source.
  const int srow = tid >> 3;
  const int scol = (((tid & 7) ^ ((tid >> 3) & 7) ^ ((tid >> 6) & 3))) << 3;
  const int soff = wv * 1024;

#define LDA(v, mt, ks) (*(const bf16x8*)(ldsA + (v)*32768 + arow + (mt)*4096 + off[ks]))
#define LDB(v, nt, ks) (*(const bf16x8*)(ldsB + (v)*32768 + brow + (nt)*4096 + off[ks]))

#define STAGE_HALF(gptr, ldsbase, h, kb) do {                                            \
    __builtin_amdgcn_global_load_lds(                                                    \
      (__attribute__((address_space(1))) void*)((gptr) + (size_t)((h)*128 + srow) * D_ + (kb) + scol), \
      (__attribute__((address_space(3))) void*)((ldsbase) + (h)*16384 + soff), 16, 0, 0);\
    __builtin_amdgcn_global_load_lds(                                                    \
      (__attribute__((address_space(1))) void*)((gptr) + (size_t)((h)*128 + 64 + srow) * D_ + (kb) + scol), \
      (__attribute__((address_space(3))) void*)((ldsbase) + (h)*16384 + 8192 + soff), 16, 0, 0); \
  } while (0)

#define SBAR()  __builtin_amdgcn_s_barrier()
#define LGK0()  asm volatile("s_waitcnt lgkmcnt(0)" ::: "memory")
#define VMC4()  asm volatile("s_waitcnt vmcnt(4)" ::: "memory")
#define VMC0()  asm volatile("s_waitcnt vmcnt(0)" ::: "memory")
#define PRIO(p) __builtin_amdgcn_s_setprio(p)

  bf16x8 a[2][4], b0[4], b1[4];
  f32x16 acc[4][2];
#pragma unroll
  for (int mt = 0; mt < 4; ++mt)
#pragma unroll
    for (int nt = 0; nt < 2; ++nt)
#pragma unroll
      for (int rr = 0; rr < 16; ++rr) acc[mt][nt][rr] = 0.f;

#define READ_A2(v, mbase) do { _Pragma("unroll") for (int mm = 0; mm < 2; ++mm) \
    _Pragma("unroll") for (int ks = 0; ks < 4; ++ks) \
      a[mm][ks] = LDA(v, (mbase) + mm, ks); } while (0)
#define READ_B4(v, nt, bb) do { _Pragma("unroll") for (int ks = 0; ks < 4; ++ks) \
      bb[ks] = LDB(v, nt, ks); } while (0)
  // ks outer / mm inner: dependent MFMAs on the same acc are spaced by an
  // independent one; per-acc accumulation order unchanged (ks 0..3).
#define MFMA_O(mbase, nt, bb) do { \
    _Pragma("unroll") for (int ks = 0; ks < 4; ++ks) \
    _Pragma("unroll") for (int mm = 0; mm < 2; ++mm) \
      acc[(mbase)+mm][nt] = __builtin_amdgcn_mfma_f32_32x32x16_bf16( \
          a[mm][ks], bb[ks], acc[(mbase)+mm][nt], 0, 0, 0); } while (0)

  // ---- prologue: tile0 B+A, tile1 B (6 halves = 12 loads); newest 2 halves
  // (tile1 B) may stay outstanding at the barrier.
  STAGE_HALF(Bg, ldsB, 0, 0);
  STAGE_HALF(Bg, ldsB, 1, 0);
  STAGE_HALF(Ag, ldsA, 0, 0);
  STAGE_HALF(Ag, ldsA, 1, 0);
  STAGE_HALF(Bg, ldsB + 32768, 0, BK64);
  STAGE_HALF(Bg, ldsB + 32768, 1, BK64);
  VMC4();
  SBAR();

  // Main loop: i = 0..NKT/2-2 (tiles 0..21); k1<=21, k2<=22, k3<=23 -> no clamp.
  for (int i = 0; i < NKT / 2 - 1; ++i) {
    const int k1 = (2 * i + 1) * BK64;
    const int k2 = (2 * i + 2) * BK64;
    const int k3 = (2 * i + 3) * BK64;

    // P1: tile 2i, quad(mt0-1 x nt0); stage A-half0(2i+1) -> buf1
    READ_A2(0, 0); READ_B4(0, 0, b0);
    STAGE_HALF(Ag, ldsA + 32768, 0, k1);
    PRIO(1); MFMA_O(0, 0, b0); PRIO(0);
    LGK0(); SBAR();
    // P2: quad(mt0-1 x nt1); stage A-half1(2i+1) -> buf1
    READ_B4(0, 1, b1);
    STAGE_HALF(Ag, ldsA + 32768, 1, k1);
    PRIO(1); MFMA_O(0, 1, b1); PRIO(0);
    LGK0(); SBAR();
    // P3: quad(mt2-3 x nt0); stage B-half0(2i+2) -> buf0
    READ_A2(0, 2);
    STAGE_HALF(Bg, ldsB, 0, k2);
    PRIO(1); MFMA_O(2, 0, b0); PRIO(0);
    LGK0(); SBAR();
    // P4: quad(mt2-3 x nt1); stage B-half1(2i+2); checkpoint vmcnt(4)
    STAGE_HALF(Bg, ldsB, 1, k2);
    PRIO(1); MFMA_O(2, 1, b1); PRIO(0);
    VMC4();
    SBAR();
    // P5: tile 2i+1, quad(mt0-1 x nt0); stage A-half0(2i+2) -> buf0
    READ_A2(1, 0); READ_B4(1, 0, b0);
    STAGE_HALF(Ag, ldsA, 0, k2);
    PRIO(1); MFMA_O(0, 0, b0); PRIO(0);
    LGK0(); SBAR();
    // P6: quad(mt0-1 x nt1); stage A-half1(2i+2) -> buf0
    READ_B4(1, 1, b1);
    STAGE_HALF(Ag, ldsA, 1, k2);
    PRIO(1); MFMA_O(0, 1, b1); PRIO(0);
    LGK0(); SBAR();
    // P7: quad(mt2-3 x nt0); stage B-half0(2i+3) -> buf1
    READ_A2(1, 2);
    STAGE_HALF(Bg, ldsB + 32768, 0, k3);
    PRIO(1); MFMA_O(2, 0, b0); PRIO(0);
    LGK0(); SBAR();
    // P8: quad(mt2-3 x nt1); stage B-half1(2i+3); checkpoint vmcnt(4)
    STAGE_HALF(Bg, ldsB + 32768, 1, k3);
    PRIO(1); MFMA_O(2, 1, b1); PRIO(0);
    VMC4();
    SBAR();
  }

  // ---- peeled last iteration (tiles 22 in buf0, 23 in buf1).
  // Entering: B(23) fully issued (i=10 P7/P8; vmcnt(4) left exactly those 4).
  // Only A(23) still needs staging (P1/P2). No other stages.
  {
    const int k1 = (NKT - 1) * BK64;   // 23*64
    // P1
    READ_A2(0, 0); READ_B4(0, 0, b0);
    STAGE_HALF(Ag, ldsA + 32768, 0, k1);
    PRIO(1); MFMA_O(0, 0, b0); PRIO(0);
    LGK0(); SBAR();
    // P2
    READ_B4(0, 1, b1);
    STAGE_HALF(Ag, ldsA + 32768, 1, k1);
    PRIO(1); MFMA_O(0, 1, b1); PRIO(0);
    LGK0(); SBAR();
    // P3
    READ_A2(0, 2);
    PRIO(1); MFMA_O(2, 0, b0); PRIO(0);
    LGK0(); SBAR();
    // P4: drain everything (B(23): 6+ phases old; A(23): 2-3 phases old)
    PRIO(1); MFMA_O(2, 1, b1); PRIO(0);
    VMC0();
    SBAR();
    // P5
    READ_A2(1, 0); READ_B4(1, 0, b0);
    PRIO(1); MFMA_O(0, 0, b0); PRIO(0);
    LGK0(); SBAR();
    // P6
    READ_B4(1, 1, b1);
    PRIO(1); MFMA_O(0, 1, b1); PRIO(0);
    LGK0(); SBAR();
    // P7
    READ_A2(1, 2);
    PRIO(1); MFMA_O(2, 0, b0); PRIO(0);
    LGK0();
    // P8 (no barrier / no drain needed before epilogue: acc-only from here)
    PRIO(1); MFMA_O(2, 1, b1); PRIO(0);
  }

  // epilogue: 32x32 C/D layout col = lane&31, row = (reg&3)+8*(reg>>2)+4*(lane>>5)
  float* Og = out + (size_t)batch * S_ * OUT_ + (size_t)m0 * OUT_ + n0;
  const float* bbase = bias + (size_t)org * OUT_ + n0;
#pragma unroll
  for (int nt = 0; nt < 2; ++nt) {
    const int col = wc * 64 + nt * 32 + l31;
    const float bv = bbase[col];
#pragma unroll
    for (int mt = 0; mt < 4; ++mt) {
#pragma unroll
      for (int rr = 0; rr < 16; ++rr) {
        const int row = wr * 128 + mt * 32 + 4 * hi + (rr & 3) + 8 * (rr >> 2);
        Og[(size_t)row * OUT_ + col] = acc[mt][nt][rr] + bv;
      }
    }
  }
#undef LDA
#undef LDB
#undef STAGE_HALF
#undef SBAR
#undef LGK0
#undef VMC4
#undef VMC0
#undef PRIO
#undef READ_A2
#undef READ_B4
#undef MFMA_O
}

// ---------------- fallback: naive fp32 (only if ws too small) ---------------
__global__ void k_gemm_fallback(const float* __restrict__ x, const int* __restrict__ oidx,
                                const float* __restrict__ w, const float* __restrict__ bias,
                                float* __restrict__ out) {
  const int b = blockIdx.z;
  const int org = oidx[b];
  const int n = blockIdx.x * 64 + threadIdx.x;
  const int m = blockIdx.y * 4 + threadIdx.y;
  const float* xr = x + ((size_t)b * S_ + m) * D_;
  const float* wp = w + (size_t)org * D_ * OUT_ + n;
  float acc = 0.f;
  for (int k = 0; k < D_; ++k) acc += xr[k] * wp[(size_t)k * OUT_];
  out[((size_t)b * S_ + m) * OUT_ + n] = acc + bias[(size_t)org * OUT_ + n];
}

extern "C" void kernel_launch(void* const* d_in, const int* in_sizes, int n_in,
                              void* d_out, int out_size, void* d_ws, size_t ws_size,
                              hipStream_t stream) {
  const float* x    = (const float*)d_in[0];
  const int*   oidx = (const int*)d_in[1];
  const float* w    = (const float*)d_in[2];
  const float* bias = (const float*)d_in[3];
  float* out = (float*)d_out;

  const size_t xb_elems = (size_t)B_ * S_ * D_;      // 50,331,648
  const size_t wt_elems = (size_t)ORG_ * OUT_ * D_;  // 12,582,912
  const size_t need = (xb_elems + wt_elems) * sizeof(bf16);  // ~126 MB

  if (ws_size < need) {
    dim3 g(OUT_ / 64, S_ / 4, B_);
    k_gemm_fallback<<<g, dim3(64, 4), 0, stream>>>(x, oidx, w, bias, out);
    return;
  }

  bf16* xb = (bf16*)d_ws;
  bf16* wt = xb + xb_elems;

  k_cvt_all<<<XBLKS + WTBLK, 256, 0, stream>>>(x, xb, w, wt);
  dim3 gg(128, B_);
  k_gemm256<<<gg, 512, 0, stream>>>(xb, wt, oidx, bias, out);
}

// Round 14
// 263.088 us; speedup vs baseline: 1.0426x; 1.0349x over previous
//
#include <hip/hip_runtime.h>
#include <hip/hip_bf16.h>
#include <stdint.h>

#define B_    8
#define S_    4096
#define D_    1536
#define ORG_  4
#define OUT_  2048

typedef __bf16 bf16;
typedef __attribute__((ext_vector_type(8)))  bf16  bf16x8;
typedef __attribute__((ext_vector_type(4)))  float f32x4n;   // native vec for nt builtins
typedef __attribute__((ext_vector_type(16))) float f32x16;

#define BK64 64
#define NKT  (D_ / BK64)   // 24 K-tiles

#define XBLKS 2048                       // blocks doing the x-stream part
#define WTBLK (ORG_ * (OUT_/32) * (D_/32))  // 12288 blocks doing w-transpose

// ---- merged convert: x f32->bf16 stream  +  w f32 [O][D][OUT] -> bf16 [O][OUT][D]
// x and w are read-once -> nontemporal loads (keep xb/wt resident for GEMM).
__global__ void k_cvt_all(const float* __restrict__ x, bf16* __restrict__ xb,
                          const float* __restrict__ w, bf16* __restrict__ wt) {
  __shared__ float tile[32][33];
  const int bx = blockIdx.x;
  const int tid = threadIdx.x;

  if (bx < XBLKS) {
    // -------- x part: 8 elems/thread/iter, grid-stride --------
    const long n8 = (long)B_ * S_ * D_ / 8;   // 6,291,456
    long i = (long)bx * blockDim.x + tid;
    const long stride = (long)XBLKS * blockDim.x;
    for (; i < n8; i += stride) {
      const f32x4n* p = (const f32x4n*)(x + i * 8);
      f32x4n a = __builtin_nontemporal_load(p);
      f32x4n b = __builtin_nontemporal_load(p + 1);
      bf16x8 v;
      v[0] = (bf16)a[0]; v[1] = (bf16)a[1]; v[2] = (bf16)a[2]; v[3] = (bf16)a[3];
      v[4] = (bf16)b[0]; v[5] = (bf16)b[1]; v[6] = (bf16)b[2]; v[7] = (bf16)b[3];
      *(bf16x8*)(xb + i * 8) = v;
    }
  } else {
    // -------- w part: 32x32 tile transpose --------
    const int q   = bx - XBLKS;
    const int org = q / ((OUT_/32) * (D_/32));
    const int rem = q % ((OUT_/32) * (D_/32));
    const int d0  = (rem / (OUT_/32)) * 32;
    const int n0  = (rem % (OUT_/32)) * 32;
    const int tx = tid & 31, ty = tid >> 5;   // 32 x 8
    const float* wsrc = w + (size_t)org * D_ * OUT_;
    bf16* wdst = wt + (size_t)org * OUT_ * D_;
#pragma unroll
    for (int j = 0; j < 32; j += 8)
      tile[ty + j][tx] = __builtin_nontemporal_load(
          wsrc + (size_t)(d0 + ty + j) * OUT_ + (n0 + tx));
    __syncthreads();
#pragma unroll
    for (int j = 0; j < 32; j += 8)
      wdst[(size_t)(n0 + ty + j) * D_ + (d0 + tx)] = (bf16)tile[tx][ty + j];
  }
}

// ----- 256x256 8-phase bf16 MFMA GEMM, 32x32x16, ONE barrier per phase ------
// A = xb[batch] : [S][D] row-major;  B = wt[org] : [OUT][D] row-major (B^T)
// C[m][n] = sum_k A[m][k]*B[n][k]  + bias[n]
// Round-13 schedule (verified). NEW r14: intra-XCD tile order inverted so the
// A-panels (the big stream) are L2-resident: XCD x runs tm in {2x,2x+1} x all
// 8 tn -> concurrent A-footprint 3MB < 4MB L2, each A-panel L2-hit 8x.
// (Old mapping kept B resident (6MB) and re-fetched A every block: FETCH 414MB.)
__global__ __launch_bounds__(512, 2)
void k_gemm256(const bf16* __restrict__ xb, const bf16* __restrict__ wt,
               const int* __restrict__ oidx, const float* __restrict__ bias,
               float* __restrict__ out) {
  __shared__ __align__(16) char smem[131072];   // A: 2x32KB, B: 2x32KB
  char* const ldsA = smem;
  char* const ldsB = smem + 65536;

  const int batch = blockIdx.y;
  const int bx = blockIdx.x;
  // T1: XCD-aware swizzle (128 tiles, 8 XCDs); bijective: swz in 0..127.
  const int swz = (bx & 7) * 16 + (bx >> 3);
  const int tm = swz >> 3, tn = swz & 7;   // r14: A-resident order (was tn=swz>>4)
  const int m0 = tm * 256, n0 = tn * 256;
  const int org = oidx[batch];

  const bf16* Ag = xb + (size_t)batch * S_ * D_ + (size_t)m0 * D_;
  const bf16* Bg = wt + (size_t)org * OUT_ * D_ + (size_t)n0 * D_;

  const int tid  = threadIdx.x;
  const int lane = tid & 63, wv = tid >> 6;
  const int wr = wv >> 2, wc = wv & 3;        // 2x4 wave grid, per-wave 128x64 out
  const int l31 = lane & 31, hi = lane >> 5;

  // Read-side swizzle key(r) = (r&7)^((r>>3)&3) (verified conflict-free r5).
  const int xorv = ((lane & 7) ^ ((lane >> 3) & 3)) << 4;
  const int off[4] = { (0  + hi * 16) ^ xorv, (32 + hi * 16) ^ xorv,
                       (64 + hi * 16) ^ xorv, (96 + hi * 16) ^ xorv };
  const int arow = (wr * 128 + l31) * 128;    // + mt*4096
  const int brow = (wc * 64  + l31) * 128;    // + nt*4096

  // Stage-side: linear LDS dest + inverse-swizzled per-lane GLOBAL source.
  const int srow = tid >> 3;
  const int scol = (((tid & 7) ^ ((tid >> 3) & 7) ^ ((tid >> 6) & 3))) << 3;
  const int soff = wv * 1024;

#define LDA(v, mt, ks) (*(const bf16x8*)(ldsA + (v)*32768 + arow + (mt)*4096 + off[ks]))
#define LDB(v, nt, ks) (*(const bf16x8*)(ldsB + (v)*32768 + brow + (nt)*4096 + off[ks]))

#define STAGE_HALF(gptr, ldsbase, h, kb) do {                                            \
    __builtin_amdgcn_global_load_lds(                                                    \
      (__attribute__((address_space(1))) void*)((gptr) + (size_t)((h)*128 + srow) * D_ + (kb) + scol), \
      (__attribute__((address_space(3))) void*)((ldsbase) + (h)*16384 + soff), 16, 0, 0);\
    __builtin_amdgcn_global_load_lds(                                                    \
      (__attribute__((address_space(1))) void*)((gptr) + (size_t)((h)*128 + 64 + srow) * D_ + (kb) + scol), \
      (__attribute__((address_space(3))) void*)((ldsbase) + (h)*16384 + 8192 + soff), 16, 0, 0); \
  } while (0)

#define SBAR()  __builtin_amdgcn_s_barrier()
#define LGK0()  asm volatile("s_waitcnt lgkmcnt(0)" ::: "memory")
#define VMC4()  asm volatile("s_waitcnt vmcnt(4)" ::: "memory")
#define VMC0()  asm volatile("s_waitcnt vmcnt(0)" ::: "memory")
#define PRIO(p) __builtin_amdgcn_s_setprio(p)

  bf16x8 a[2][4], b0[4], b1[4];
  f32x16 acc[4][2];
#pragma unroll
  for (int mt = 0; mt < 4; ++mt)
#pragma unroll
    for (int nt = 0; nt < 2; ++nt)
#pragma unroll
      for (int rr = 0; rr < 16; ++rr) acc[mt][nt][rr] = 0.f;

#define READ_A2(v, mbase) do { _Pragma("unroll") for (int mm = 0; mm < 2; ++mm) \
    _Pragma("unroll") for (int ks = 0; ks < 4; ++ks) \
      a[mm][ks] = LDA(v, (mbase) + mm, ks); } while (0)
#define READ_B4(v, nt, bb) do { _Pragma("unroll") for (int ks = 0; ks < 4; ++ks) \
      bb[ks] = LDB(v, nt, ks); } while (0)
  // ks outer / mm inner: dependent MFMAs on the same acc are spaced by an
  // independent one; per-acc accumulation order unchanged (ks 0..3).
#define MFMA_O(mbase, nt, bb) do { \
    _Pragma("unroll") for (int ks = 0; ks < 4; ++ks) \
    _Pragma("unroll") for (int mm = 0; mm < 2; ++mm) \
      acc[(mbase)+mm][nt] = __builtin_amdgcn_mfma_f32_32x32x16_bf16( \
          a[mm][ks], bb[ks], acc[(mbase)+mm][nt], 0, 0, 0); } while (0)

  // ---- prologue: tile0 B+A, tile1 B (6 halves = 12 loads); newest 2 halves
  // (tile1 B) may stay outstanding at the barrier.
  STAGE_HALF(Bg, ldsB, 0, 0);
  STAGE_HALF(Bg, ldsB, 1, 0);
  STAGE_HALF(Ag, ldsA, 0, 0);
  STAGE_HALF(Ag, ldsA, 1, 0);
  STAGE_HALF(Bg, ldsB + 32768, 0, BK64);
  STAGE_HALF(Bg, ldsB + 32768, 1, BK64);
  VMC4();
  SBAR();

  // Main loop: i = 0..NKT/2-2 (tiles 0..21); k1<=21, k2<=22, k3<=23 -> no clamp.
  for (int i = 0; i < NKT / 2 - 1; ++i) {
    const int k1 = (2 * i + 1) * BK64;
    const int k2 = (2 * i + 2) * BK64;
    const int k3 = (2 * i + 3) * BK64;

    // P1: tile 2i, quad(mt0-1 x nt0); stage A-half0(2i+1) -> buf1
    READ_A2(0, 0); READ_B4(0, 0, b0);
    STAGE_HALF(Ag, ldsA + 32768, 0, k1);
    PRIO(1); MFMA_O(0, 0, b0); PRIO(0);
    LGK0(); SBAR();
    // P2: quad(mt0-1 x nt1); stage A-half1(2i+1) -> buf1
    READ_B4(0, 1, b1);
    STAGE_HALF(Ag, ldsA + 32768, 1, k1);
    PRIO(1); MFMA_O(0, 1, b1); PRIO(0);
    LGK0(); SBAR();
    // P3: quad(mt2-3 x nt0); stage B-half0(2i+2) -> buf0
    READ_A2(0, 2);
    STAGE_HALF(Bg, ldsB, 0, k2);
    PRIO(1); MFMA_O(2, 0, b0); PRIO(0);
    LGK0(); SBAR();
    // P4: quad(mt2-3 x nt1); stage B-half1(2i+2); checkpoint vmcnt(4)
    STAGE_HALF(Bg, ldsB, 1, k2);
    PRIO(1); MFMA_O(2, 1, b1); PRIO(0);
    VMC4();
    SBAR();
    // P5: tile 2i+1, quad(mt0-1 x nt0); stage A-half0(2i+2) -> buf0
    READ_A2(1, 0); READ_B4(1, 0, b0);
    STAGE_HALF(Ag, ldsA, 0, k2);
    PRIO(1); MFMA_O(0, 0, b0); PRIO(0);
    LGK0(); SBAR();
    // P6: quad(mt0-1 x nt1); stage A-half1(2i+2) -> buf0
    READ_B4(1, 1, b1);
    STAGE_HALF(Ag, ldsA, 1, k2);
    PRIO(1); MFMA_O(0, 1, b1); PRIO(0);
    LGK0(); SBAR();
    // P7: quad(mt2-3 x nt0); stage B-half0(2i+3) -> buf1
    READ_A2(1, 2);
    STAGE_HALF(Bg, ldsB + 32768, 0, k3);
    PRIO(1); MFMA_O(2, 0, b0); PRIO(0);
    LGK0(); SBAR();
    // P8: quad(mt2-3 x nt1); stage B-half1(2i+3); checkpoint vmcnt(4)
    STAGE_HALF(Bg, ldsB + 32768, 1, k3);
    PRIO(1); MFMA_O(2, 1, b1); PRIO(0);
    VMC4();
    SBAR();
  }

  // ---- peeled last iteration (tiles 22 in buf0, 23 in buf1).
  {
    const int k1 = (NKT - 1) * BK64;   // 23*64
    // P1
    READ_A2(0, 0); READ_B4(0, 0, b0);
    STAGE_HALF(Ag, ldsA + 32768, 0, k1);
    PRIO(1); MFMA_O(0, 0, b0); PRIO(0);
    LGK0(); SBAR();
    // P2
    READ_B4(0, 1, b1);
    STAGE_HALF(Ag, ldsA + 32768, 1, k1);
    PRIO(1); MFMA_O(0, 1, b1); PRIO(0);
    LGK0(); SBAR();
    // P3
    READ_A2(0, 2);
    PRIO(1); MFMA_O(2, 0, b0); PRIO(0);
    LGK0(); SBAR();
    // P4: drain everything (B(23): 6+ phases old; A(23): 2-3 phases old)
    PRIO(1); MFMA_O(2, 1, b1); PRIO(0);
    VMC0();
    SBAR();
    // P5
    READ_A2(1, 0); READ_B4(1, 0, b0);
    PRIO(1); MFMA_O(0, 0, b0); PRIO(0);
    LGK0(); SBAR();
    // P6
    READ_B4(1, 1, b1);
    PRIO(1); MFMA_O(0, 1, b1); PRIO(0);
    LGK0(); SBAR();
    // P7
    READ_A2(1, 2);
    PRIO(1); MFMA_O(2, 0, b0); PRIO(0);
    LGK0();
    // P8 (no barrier / no drain needed before epilogue: acc-only from here)
    PRIO(1); MFMA_O(2, 1, b1); PRIO(0);
  }

  // epilogue: 32x32 C/D layout col = lane&31, row = (reg&3)+8*(reg>>2)+4*(lane>>5)
  float* Og = out + (size_t)batch * S_ * OUT_ + (size_t)m0 * OUT_ + n0;
  const float* bbase = bias + (size_t)org * OUT_ + n0;
#pragma unroll
  for (int nt = 0; nt < 2; ++nt) {
    const int col = wc * 64 + nt * 32 + l31;
    const float bv = bbase[col];
#pragma unroll
    for (int mt = 0; mt < 4; ++mt) {
#pragma unroll
      for (int rr = 0; rr < 16; ++rr) {
        const int row = wr * 128 + mt * 32 + 4 * hi + (rr & 3) + 8 * (rr >> 2);
        Og[(size_t)row * OUT_ + col] = acc[mt][nt][rr] + bv;
      }
    }
  }
#undef LDA
#undef LDB
#undef STAGE_HALF
#undef SBAR
#undef LGK0
#undef VMC4
#undef VMC0
#undef PRIO
#undef READ_A2
#undef READ_B4
#undef MFMA_O
}

// ---------------- fallback: naive fp32 (only if ws too small) ---------------
__global__ void k_gemm_fallback(const float* __restrict__ x, const int* __restrict__ oidx,
                                const float* __restrict__ w, const float* __restrict__ bias,
                                float* __restrict__ out) {
  const int b = blockIdx.z;
  const int org = oidx[b];
  const int n = blockIdx.x * 64 + threadIdx.x;
  const int m = blockIdx.y * 4 + threadIdx.y;
  const float* xr = x + ((size_t)b * S_ + m) * D_;
  const float* wp = w + (size_t)org * D_ * OUT_ + n;
  float acc = 0.f;
  for (int k = 0; k < D_; ++k) acc += xr[k] * wp[(size_t)k * OUT_];
  out[((size_t)b * S_ + m) * OUT_ + n] = acc + bias[(size_t)org * OUT_ + n];
}

extern "C" void kernel_launch(void* const* d_in, const int* in_sizes, int n_in,
                              void* d_out, int out_size, void* d_ws, size_t ws_size,
                              hipStream_t stream) {
  const float* x    = (const float*)d_in[0];
  const int*   oidx = (const int*)d_in[1];
  const float* w    = (const float*)d_in[2];
  const float* bias = (const float*)d_in[3];
  float* out = (float*)d_out;

  const size_t xb_elems = (size_t)B_ * S_ * D_;      // 50,331,648
  const size_t wt_elems = (size_t)ORG_ * OUT_ * D_;  // 12,582,912
  const size_t need = (xb_elems + wt_elems) * sizeof(bf16);  // ~126 MB

  if (ws_size < need) {
    dim3 g(OUT_ / 64, S_ / 4, B_);
    k_gemm_fallback<<<g, dim3(64, 4), 0, stream>>>(x, oidx, w, bias, out);
    return;
  }

  bf16* xb = (bf16*)d_ws;
  bf16* wt = xb + xb_elems;

  k_cvt_all<<<XBLKS + WTBLK, 256, 0, stream>>>(x, xb, w, wt);
  dim3 gg(128, B_);
  k_gemm256<<<gg, 512, 0, stream>>>(xb, wt, oidx, bias, out);
}